// Round 1
// baseline (1710.643 us; speedup 1.0000x reference)
//
#include <hip/hip_runtime.h>

#define HH 80
#define WW 80
#define NPIX (HH*WW)      // 6400
#define CFE 64            // feature channels
#define CMA 3             // mask channels
#define KF (CFE*9)        // 576
#define KM (CMA*9)        // 27
#define BT 128            // n/m tile
#define BK 64             // k chunk
#define NT (NPIX/BT)      // 50 tiles per dim

#define NEG_INF (-__builtin_inff())

// ---------------------------------------------------------------------------
// Style-side reciprocal patch norms (content-side norms are per-row positive
// scale factors -> irrelevant for argmax -> skipped entirely).
// ---------------------------------------------------------------------------
__global__ __launch_bounds__(256)
void norms_kernel(const float* __restrict__ sf, const float* __restrict__ sm,
                  float* __restrict__ rnf, float* __restrict__ rnm) {
    int g = blockIdx.x * 256 + threadIdx.x;
    if (g >= 2 * NPIX) return;
    int b = g / NPIX, m = g - b * NPIX;
    int mh = m / WW, mw = m - mh * WW;

    const float* sfb = sf + (size_t)b * CFE * NPIX;
    const float* smb = sm + (size_t)b * CMA * NPIX;

    float accf = 0.f;
    for (int c = 0; c < CFE; ++c) {
        const float* pc = sfb + c * NPIX;
        for (int di = -1; di <= 1; ++di) {
            int h = mh + di; if ((unsigned)h >= HH) continue;
            for (int dj = -1; dj <= 1; ++dj) {
                int w = mw + dj; if ((unsigned)w >= WW) continue;
                float v = pc[h * WW + w];
                accf = fmaf(v, v, accf);
            }
        }
    }
    float accm = 0.f;
    for (int c = 0; c < CMA; ++c) {
        const float* pc = smb + c * NPIX;
        for (int di = -1; di <= 1; ++di) {
            int h = mh + di; if ((unsigned)h >= HH) continue;
            for (int dj = -1; dj <= 1; ++dj) {
                int w = mw + dj; if ((unsigned)w >= WW) continue;
                float v = pc[h * WW + w];
                accm = fmaf(v, v, accm);
            }
        }
    }
    rnf[g] = 1.f / fmaxf(sqrtf(accf), 1e-12f);
    rnm[g] = 1.f / fmaxf(sqrtf(accm), 1e-12f);
}

// ---------------------------------------------------------------------------
// Main tiled similarity + per-tile argmax.
// Block = (mtile, ntile, b). 256 threads, 8x8 fp32 accumulators (feat + mask).
// Writes per-row (best_val, best_idx) partial for this m-tile chunk.
// ---------------------------------------------------------------------------
__global__ __launch_bounds__(256)
void sim_kernel(const float* __restrict__ cf, const float* __restrict__ sf,
                const float* __restrict__ cm, const float* __restrict__ sm,
                const float* __restrict__ rnf, const float* __restrict__ rnm,
                float* __restrict__ pval, int* __restrict__ pidx) {
    __shared__ float As[BK][BT];
    __shared__ float Bs[BK][BT];

    const int b  = blockIdx.z;
    const int n0 = blockIdx.y * BT;
    const int m0 = blockIdx.x * BT;
    const int tid = threadIdx.x;
    const int ty = tid >> 4, tx = tid & 15;

    // staging: each thread owns one fixed pixel column p, two k-rows per step
    const int p   = tid & 127;
    const int k00 = tid >> 7;

    const int nA = n0 + p; const int nhA = nA / WW; const int nwA = nA - nhA * WW;
    const int mB = m0 + p; const int mhB = mB / WW; const int mwB = mB - mhB * WW;

    const float* __restrict__ cfb = cf + (size_t)b * CFE * NPIX;
    const float* __restrict__ sfb = sf + (size_t)b * CFE * NPIX;
    const float* __restrict__ cmb = cm + (size_t)b * CMA * NPIX;
    const float* __restrict__ smb = sm + (size_t)b * CMA * NPIX;

    float accF[8][8];
    float accM[8][8];
    #pragma unroll
    for (int i = 0; i < 8; ++i)
        #pragma unroll
        for (int j = 0; j < 8; ++j) { accF[i][j] = 0.f; accM[i][j] = 0.f; }

    // ---- feature dot: K = 576 in 9 chunks of 64
    for (int k0 = 0; k0 < KF; k0 += BK) {
        __syncthreads();
        #pragma unroll 4
        for (int kk = k00; kk < BK; kk += 2) {
            int kg = k0 + kk;
            int c = kg / 9, pos = kg - c * 9;
            int di = pos / 3 - 1, dj = pos - (pos / 3) * 3 - 1;
            int h = nhA + di, w = nwA + dj;
            As[kk][p] = ((unsigned)h < HH && (unsigned)w < WW) ? cfb[c * NPIX + h * WW + w] : 0.f;
            h = mhB + di; w = mwB + dj;
            Bs[kk][p] = ((unsigned)h < HH && (unsigned)w < WW) ? sfb[c * NPIX + h * WW + w] : 0.f;
        }
        __syncthreads();
        #pragma unroll 4
        for (int k = 0; k < BK; ++k) {
            float a[8], bb[8];
            *(float4*)&a[0]  = *(const float4*)&As[k][ty * 4];
            *(float4*)&a[4]  = *(const float4*)&As[k][64 + ty * 4];
            *(float4*)&bb[0] = *(const float4*)&Bs[k][tx * 4];
            *(float4*)&bb[4] = *(const float4*)&Bs[k][64 + tx * 4];
            #pragma unroll
            for (int i = 0; i < 8; ++i)
                #pragma unroll
                for (int j = 0; j < 8; ++j)
                    accF[i][j] = fmaf(a[i], bb[j], accF[i][j]);
        }
    }

    // ---- mask dot: K = 27, single chunk
    __syncthreads();
    for (int kk = k00; kk < KM; kk += 2) {
        int c = kk / 9, pos = kk - c * 9;
        int di = pos / 3 - 1, dj = pos - (pos / 3) * 3 - 1;
        int h = nhA + di, w = nwA + dj;
        As[kk][p] = ((unsigned)h < HH && (unsigned)w < WW) ? cmb[c * NPIX + h * WW + w] : 0.f;
        h = mhB + di; w = mwB + dj;
        Bs[kk][p] = ((unsigned)h < HH && (unsigned)w < WW) ? smb[c * NPIX + h * WW + w] : 0.f;
    }
    __syncthreads();
    #pragma unroll 3
    for (int k = 0; k < KM; ++k) {
        float a[8], bb[8];
        *(float4*)&a[0]  = *(const float4*)&As[k][ty * 4];
        *(float4*)&a[4]  = *(const float4*)&As[k][64 + ty * 4];
        *(float4*)&bb[0] = *(const float4*)&Bs[k][tx * 4];
        *(float4*)&bb[4] = *(const float4*)&Bs[k][64 + tx * 4];
        #pragma unroll
        for (int i = 0; i < 8; ++i)
            #pragma unroll
            for (int j = 0; j < 8; ++j)
                accM[i][j] = fmaf(a[i], bb[j], accM[i][j]);
    }

    // ---- epilogue: score = dotF * rnf_s[m] * dotM * rnm_s[m]; per-row argmax
    float rvF[8], rvM[8];
    #pragma unroll
    for (int j = 0; j < 8; ++j) {
        int col = (j < 4) ? (tx * 4 + j) : (64 + tx * 4 + (j - 4));
        int m = m0 + col;
        rvF[j] = rnf[b * NPIX + m];
        rvM[j] = rnm[b * NPIX + m];
    }
    float bv[8]; int bi[8];
    #pragma unroll
    for (int i = 0; i < 8; ++i) { bv[i] = NEG_INF; bi[i] = 0x7fffffff; }
    #pragma unroll
    for (int j = 0; j < 8; ++j) {          // cols ascending within thread
        int col = (j < 4) ? (tx * 4 + j) : (64 + tx * 4 + (j - 4));
        int m = m0 + col;
        #pragma unroll
        for (int i = 0; i < 8; ++i) {
            float s = (accF[i][j] * rvF[j]) * (accM[i][j] * rvM[j]);
            if (s > bv[i]) { bv[i] = s; bi[i] = m; }   // strict > keeps first
        }
    }

    // cross-thread (tx) reduction via LDS reuse
    __syncthreads();
    float* rv = &As[0][0];                 // 128*16 floats, fits easily
    int*   ri = (int*)&Bs[0][0];
    #pragma unroll
    for (int i = 0; i < 8; ++i) {
        int r = (i < 4) ? (ty * 4 + i) : (64 + ty * 4 + (i - 4));
        rv[r * 16 + tx] = bv[i];
        ri[r * 16 + tx] = bi[i];
    }
    __syncthreads();
    if (tid < 128) {
        int r = tid;
        float best = rv[r * 16]; int besti = ri[r * 16];
        #pragma unroll 4
        for (int t = 1; t < 16; ++t) {
            float v = rv[r * 16 + t]; int ii = ri[r * 16 + t];
            if (v > best || (v == best && ii < besti)) { best = v; besti = ii; }
        }
        int n = n0 + r;
        pval[((size_t)b * NT + blockIdx.x) * NPIX + n] = best;
        pidx[((size_t)b * NT + blockIdx.x) * NPIX + n] = besti;
    }
}

// ---------------------------------------------------------------------------
// Final reduce over the NT m-tile partials + gather of the winning patch.
// One 64-thread block per (n, b).
// ---------------------------------------------------------------------------
__global__ __launch_bounds__(64)
void gather_kernel(const float* __restrict__ sf,
                   const float* __restrict__ pval, const int* __restrict__ pidx,
                   float* __restrict__ out) {
    int n = blockIdx.x, b = blockIdx.y;
    int lane = threadIdx.x;

    float v = NEG_INF; int idx = 0x7fffffff;
    if (lane < NT) {
        v   = pval[((size_t)b * NT + lane) * NPIX + n];
        idx = pidx[((size_t)b * NT + lane) * NPIX + n];
    }
    #pragma unroll
    for (int off = 32; off >= 1; off >>= 1) {
        float ov = __shfl_xor(v, off);
        int   oi = __shfl_xor(idx, off);
        if (ov > v || (ov == v && oi < idx)) { v = ov; idx = oi; }
    }

    int m = idx; int mh = m / WW, mw = m - mh * WW;
    const float* sfb = sf + (size_t)b * CFE * NPIX;
    float* ob = out + ((size_t)b * NPIX + n) * (size_t)KF;
    #pragma unroll
    for (int e = lane; e < KF; e += 64) {   // 9 elements per lane
        int c = e / 9, pos = e - c * 9;
        int di = pos / 3 - 1, dj = pos - (pos / 3) * 3 - 1;
        int h = mh + di, w = mw + dj;
        ob[e] = ((unsigned)h < HH && (unsigned)w < WW) ? sfb[c * NPIX + h * WW + w] : 0.f;
    }
}

// ---------------------------------------------------------------------------
extern "C" void kernel_launch(void* const* d_in, const int* in_sizes, int n_in,
                              void* d_out, int out_size, void* d_ws, size_t ws_size,
                              hipStream_t stream) {
    const float* cf = (const float*)d_in[0];   // content_feat [2,64,80,80]
    const float* sf = (const float*)d_in[1];   // style_feat   [2,64,80,80]
    const float* cm = (const float*)d_in[2];   // content_mask [2,3,80,80]
    const float* sm = (const float*)d_in[3];   // style_mask   [2,3,80,80]
    float* out = (float*)d_out;                // [2,6400,64,3,3] fp32

    // ws layout (floats): rnf[2*6400] | rnm[2*6400] | pval[2*50*6400] | pidx[2*50*6400]
    float* rnf  = (float*)d_ws;
    float* rnm  = rnf + 2 * NPIX;
    float* pval = rnm + 2 * NPIX;
    int*   pidx = (int*)(pval + (size_t)2 * NT * NPIX);

    norms_kernel<<<(2 * NPIX + 255) / 256, 256, 0, stream>>>(sf, sm, rnf, rnm);
    sim_kernel<<<dim3(NT, NT, 2), 256, 0, stream>>>(cf, sf, cm, sm, rnf, rnm, pval, pidx);
    gather_kernel<<<dim3(NPIX, 2), 64, 0, stream>>>(sf, pval, pidx, out);
}

// Round 2
// 1281.552 us; speedup vs baseline: 1.3348x; 1.3348x over previous
//
#include <hip/hip_runtime.h>

#define HH 80
#define WW 80
#define NPIX (HH*WW)      // 6400
#define CFE 64            // feature channels
#define CMA 3             // mask channels
#define KF (CFE*9)        // 576
#define KM (CMA*9)        // 27
#define BT 128            // n/m tile
#define NT (NPIX/BT)      // 50 tiles per dim

#define NEG_INF (-__builtin_inff())

// direct global -> LDS, 4 bytes per lane; dst = uniform base + lane*4
__device__ __forceinline__ void gload4(const float* g, float* l) {
    __builtin_amdgcn_global_load_lds((const __attribute__((address_space(1))) void*)g,
                                     (__attribute__((address_space(3))) void*)l, 4, 0, 0);
}

// ---------------------------------------------------------------------------
// Style-side reciprocal patch norms (content-side norms are per-row positive
// scale factors -> irrelevant for argmax -> skipped entirely).
// ---------------------------------------------------------------------------
__global__ __launch_bounds__(256)
void norms_kernel(const float* __restrict__ sf, const float* __restrict__ sm,
                  float* __restrict__ rnf, float* __restrict__ rnm) {
    int g = blockIdx.x * 256 + threadIdx.x;
    if (g >= 2 * NPIX) return;
    int b = g / NPIX, m = g - b * NPIX;
    int mh = m / WW, mw = m - mh * WW;

    const float* sfb = sf + (size_t)b * CFE * NPIX;
    const float* smb = sm + (size_t)b * CMA * NPIX;

    float accf = 0.f;
    for (int c = 0; c < CFE; ++c) {
        const float* pc = sfb + c * NPIX;
        for (int di = -1; di <= 1; ++di) {
            int h = mh + di; if ((unsigned)h >= HH) continue;
            for (int dj = -1; dj <= 1; ++dj) {
                int w = mw + dj; if ((unsigned)w >= WW) continue;
                float v = pc[h * WW + w];
                accf = fmaf(v, v, accf);
            }
        }
    }
    float accm = 0.f;
    for (int c = 0; c < CMA; ++c) {
        const float* pc = smb + c * NPIX;
        for (int di = -1; di <= 1; ++di) {
            int h = mh + di; if ((unsigned)h >= HH) continue;
            for (int dj = -1; dj <= 1; ++dj) {
                int w = mw + dj; if ((unsigned)w >= WW) continue;
                float v = pc[h * WW + w];
                accm = fmaf(v, v, accm);
            }
        }
    }
    rnf[g] = 1.f / fmaxf(sqrtf(accf), 1e-12f);
    rnm[g] = 1.f / fmaxf(sqrtf(accm), 1e-12f);
}

// ---------------------------------------------------------------------------
// Main tiled similarity + per-tile argmax.
// K reordered as (shift, channel): 9 shifts x 2 half-chunks of 32 channels.
// Within a chunk the shift delta is constant -> rows are contiguous loads,
// boundary mask is per-column only -> zero-page redirect, global_load_lds.
// ---------------------------------------------------------------------------
__global__ __launch_bounds__(256, 3)
void sim_kernel(const float* __restrict__ cf, const float* __restrict__ sf,
                const float* __restrict__ cm, const float* __restrict__ sm,
                const float* __restrict__ rnf, const float* __restrict__ rnm,
                const float* __restrict__ zp,
                float* __restrict__ pval, int* __restrict__ pidx) {
    __shared__ float As[32][BT];
    __shared__ float Bs[32][BT];

    const int b  = blockIdx.z;
    const int n0 = blockIdx.y * BT;
    const int m0 = blockIdx.x * BT;
    const int tid = threadIdx.x;
    const int ty = tid >> 4, tx = tid & 15;
    const int wv = tid >> 6;          // wave 0..3
    const int ln = tid & 63;          // lane 0..63

    // each lane owns two staging columns (h = 0,1): col = ln + 64*h
    int nA[2], nhA[2], nwA[2], mB[2], mhB[2], mwB[2];
    #pragma unroll
    for (int h = 0; h < 2; ++h) {
        nA[h] = n0 + ln + 64 * h; nhA[h] = nA[h] / WW; nwA[h] = nA[h] - nhA[h] * WW;
        mB[h] = m0 + ln + 64 * h; mhB[h] = mB[h] / WW; mwB[h] = mB[h] - mhB[h] * WW;
    }

    const float* __restrict__ cfb = cf + (size_t)b * CFE * NPIX;
    const float* __restrict__ sfb = sf + (size_t)b * CFE * NPIX;

    float accF[8][8];
    #pragma unroll
    for (int i = 0; i < 8; ++i)
        #pragma unroll
        for (int j = 0; j < 8; ++j) accF[i][j] = 0.f;

    // ---- feature dot: 9 shifts x 2 chunks of 32 channels
    #pragma unroll 1
    for (int s = 0; s < 9; ++s) {
        const int di = s / 3 - 1;
        const int dj = s - (s / 3) * 3 - 1;
        const int dlt = di * WW + dj;

        bool badA[2], badB[2];
        #pragma unroll
        for (int h = 0; h < 2; ++h) {
            badA[h] = ((unsigned)(nhA[h] + di) >= HH) || ((unsigned)(nwA[h] + dj) >= WW);
            badB[h] = ((unsigned)(mhB[h] + di) >= HH) || ((unsigned)(mwB[h] + dj) >= WW);
        }

        #pragma unroll 1
        for (int half = 0; half < 2; ++half) {
            __syncthreads();                  // previous compute done with LDS
            const int c0 = half * 32 + 8 * wv;   // this wave's first channel row

            #pragma unroll
            for (int h = 0; h < 2; ++h) {
                const float* g = badA[h] ? zp : (cfb + (size_t)c0 * NPIX + nA[h] + dlt);
                const int str  = badA[h] ? 0 : NPIX;
                float* dst = &As[8 * wv][h * 64];
                #pragma unroll
                for (int r = 0; r < 8; ++r) { gload4(g, dst); g += str; dst += BT; }
            }
            #pragma unroll
            for (int h = 0; h < 2; ++h) {
                const float* g = badB[h] ? zp : (sfb + (size_t)c0 * NPIX + mB[h] + dlt);
                const int str  = badB[h] ? 0 : NPIX;
                float* dst = &Bs[8 * wv][h * 64];
                #pragma unroll
                for (int r = 0; r < 8; ++r) { gload4(g, dst); g += str; dst += BT; }
            }
            __syncthreads();                  // drains vmcnt -> LDS ready

            #pragma unroll 4
            for (int k = 0; k < 32; ++k) {
                float a[8], bb[8];
                *(float4*)&a[0]  = *(const float4*)&As[k][ty * 4];
                *(float4*)&a[4]  = *(const float4*)&As[k][64 + ty * 4];
                *(float4*)&bb[0] = *(const float4*)&Bs[k][tx * 4];
                *(float4*)&bb[4] = *(const float4*)&Bs[k][64 + tx * 4];
                #pragma unroll
                for (int i = 0; i < 8; ++i)
                    #pragma unroll
                    for (int j = 0; j < 8; ++j)
                        accF[i][j] = fmaf(a[i], bb[j], accF[i][j]);
            }
        }
    }

    // ---- mask dot: K = 27, one chunk, plain staging (runs once)
    __syncthreads();
    {
        const float* __restrict__ cmb = cm + (size_t)b * CMA * NPIX;
        const float* __restrict__ smb = sm + (size_t)b * CMA * NPIX;
        for (int idx = tid; idx < KM * BT; idx += 256) {
            int r = idx >> 7, p = idx & 127;
            int c = r / 9, pos = r - c * 9;
            int di = pos / 3 - 1, dj = pos - (pos / 3) * 3 - 1;
            int n = n0 + p; int nh = n / WW, nw = n - nh * WW;
            int h = nh + di, w = nw + dj;
            As[r][p] = ((unsigned)h < HH && (unsigned)w < WW) ? cmb[c * NPIX + h * WW + w] : 0.f;
            int m = m0 + p; int mh = m / WW, mw = m - mh * WW;
            h = mh + di; w = mw + dj;
            Bs[r][p] = ((unsigned)h < HH && (unsigned)w < WW) ? smb[c * NPIX + h * WW + w] : 0.f;
        }
    }
    __syncthreads();

    float accM[8][8];
    #pragma unroll
    for (int i = 0; i < 8; ++i)
        #pragma unroll
        for (int j = 0; j < 8; ++j) accM[i][j] = 0.f;

    #pragma unroll 3
    for (int k = 0; k < KM; ++k) {
        float a[8], bb[8];
        *(float4*)&a[0]  = *(const float4*)&As[k][ty * 4];
        *(float4*)&a[4]  = *(const float4*)&As[k][64 + ty * 4];
        *(float4*)&bb[0] = *(const float4*)&Bs[k][tx * 4];
        *(float4*)&bb[4] = *(const float4*)&Bs[k][64 + tx * 4];
        #pragma unroll
        for (int i = 0; i < 8; ++i)
            #pragma unroll
            for (int j = 0; j < 8; ++j)
                accM[i][j] = fmaf(a[i], bb[j], accM[i][j]);
    }

    // ---- epilogue: score = dotF * rnf_s[m] * dotM * rnm_s[m]; per-row argmax
    float rvF[8], rvM[8];
    #pragma unroll
    for (int j = 0; j < 8; ++j) {
        int col = (j < 4) ? (tx * 4 + j) : (64 + tx * 4 + (j - 4));
        int m = m0 + col;
        rvF[j] = rnf[b * NPIX + m];
        rvM[j] = rnm[b * NPIX + m];
    }
    float bv[8]; int bi[8];
    #pragma unroll
    for (int i = 0; i < 8; ++i) { bv[i] = NEG_INF; bi[i] = 0x7fffffff; }
    #pragma unroll
    for (int j = 0; j < 8; ++j) {          // cols ascending within thread
        int col = (j < 4) ? (tx * 4 + j) : (64 + tx * 4 + (j - 4));
        int m = m0 + col;
        #pragma unroll
        for (int i = 0; i < 8; ++i) {
            float sc = (accF[i][j] * rvF[j]) * (accM[i][j] * rvM[j]);
            if (sc > bv[i]) { bv[i] = sc; bi[i] = m; }   // strict > keeps first
        }
    }

    // cross-thread (tx) reduction via LDS reuse
    __syncthreads();
    float* rv = &As[0][0];                 // 2048 floats needed, 4096 available
    int*   ri = (int*)&Bs[0][0];
    #pragma unroll
    for (int i = 0; i < 8; ++i) {
        int r = (i < 4) ? (ty * 4 + i) : (64 + ty * 4 + (i - 4));
        rv[r * 16 + tx] = bv[i];
        ri[r * 16 + tx] = bi[i];
    }
    __syncthreads();
    if (tid < 128) {
        int r = tid;
        float best = rv[r * 16]; int besti = ri[r * 16];
        #pragma unroll 4
        for (int t = 1; t < 16; ++t) {
            float v = rv[r * 16 + t]; int ii = ri[r * 16 + t];
            if (v > best || (v == best && ii < besti)) { best = v; besti = ii; }
        }
        int n = n0 + r;
        pval[((size_t)b * NT + blockIdx.x) * NPIX + n] = best;
        pidx[((size_t)b * NT + blockIdx.x) * NPIX + n] = besti;
    }
}

// ---------------------------------------------------------------------------
// Final reduce over the NT m-tile partials + gather of the winning patch.
// ---------------------------------------------------------------------------
__global__ __launch_bounds__(64)
void gather_kernel(const float* __restrict__ sf,
                   const float* __restrict__ pval, const int* __restrict__ pidx,
                   float* __restrict__ out) {
    int n = blockIdx.x, b = blockIdx.y;
    int lane = threadIdx.x;

    float v = NEG_INF; int idx = 0x7fffffff;
    if (lane < NT) {
        v   = pval[((size_t)b * NT + lane) * NPIX + n];
        idx = pidx[((size_t)b * NT + lane) * NPIX + n];
    }
    #pragma unroll
    for (int off = 32; off >= 1; off >>= 1) {
        float ov = __shfl_xor(v, off);
        int   oi = __shfl_xor(idx, off);
        if (ov > v || (ov == v && oi < idx)) { v = ov; idx = oi; }
    }

    int m = idx; int mh = m / WW, mw = m - mh * WW;
    const float* sfb = sf + (size_t)b * CFE * NPIX;
    float* ob = out + ((size_t)b * NPIX + n) * (size_t)KF;
    #pragma unroll
    for (int e = lane; e < KF; e += 64) {   // 9 elements per lane
        int c = e / 9, pos = e - c * 9;
        int di = pos / 3 - 1, dj = pos - (pos / 3) * 3 - 1;
        int h = mh + di, w = mw + dj;
        ob[e] = ((unsigned)h < HH && (unsigned)w < WW) ? sfb[c * NPIX + h * WW + w] : 0.f;
    }
}

// ---------------------------------------------------------------------------
extern "C" void kernel_launch(void* const* d_in, const int* in_sizes, int n_in,
                              void* d_out, int out_size, void* d_ws, size_t ws_size,
                              hipStream_t stream) {
    const float* cf = (const float*)d_in[0];   // content_feat [2,64,80,80]
    const float* sf = (const float*)d_in[1];   // style_feat   [2,64,80,80]
    const float* cm = (const float*)d_in[2];   // content_mask [2,3,80,80]
    const float* sm = (const float*)d_in[3];   // style_mask   [2,3,80,80]
    float* out = (float*)d_out;                // [2,6400,64,3,3] fp32

    // ws layout (floats): zp[64] | rnf[2*6400] | rnm[2*6400] | pval | pidx
    float* zp   = (float*)d_ws;
    float* rnf  = zp + 64;
    float* rnm  = rnf + 2 * NPIX;
    float* pval = rnm + 2 * NPIX;
    int*   pidx = (int*)(pval + (size_t)2 * NT * NPIX);

    hipMemsetAsync(zp, 0, 256, stream);        // zero page for masked lanes

    norms_kernel<<<(2 * NPIX + 255) / 256, 256, 0, stream>>>(sf, sm, rnf, rnm);
    sim_kernel<<<dim3(NT, NT, 2), 256, 0, stream>>>(cf, sf, cm, sm, rnf, rnm, zp, pval, pidx);
    gather_kernel<<<dim3(NPIX, 2), 64, 0, stream>>>(sf, pval, pidx, out);
}

// Round 3
// 935.122 us; speedup vs baseline: 1.8293x; 1.3705x over previous
//
#include <hip/hip_runtime.h>

#define HH 80
#define WW 80
#define NPIX 6400
#define CFE 64
#define CMA 3
#define KF 576
#define NT 50              // global 128-col tiles
#define NEG_INF (-__builtin_inff())

// 16B load with only 4B alignment guarantee (backend emits dwordx4; dword align ok)
struct f4u { float x, y, z, w; };

__device__ __forceinline__ void gload4(const float* g, float* l) {
    __builtin_amdgcn_global_load_lds((const __attribute__((address_space(1))) void*)g,
                                     (__attribute__((address_space(3))) void*)l, 4, 0, 0);
}

// ---------------------------------------------------------------------------
// per-pixel channel-sum-of-squares (style side only)
// ---------------------------------------------------------------------------
__global__ __launch_bounds__(256)
void pixsq_kernel(const float* __restrict__ sf, const float* __restrict__ sm,
                  float* __restrict__ psf, float* __restrict__ psm) {
    int g = blockIdx.x * 256 + threadIdx.x;
    if (g >= 2 * NPIX) return;
    int b = g / NPIX, m = g - b * NPIX;
    const float* p = sf + (size_t)b * CFE * NPIX + m;
    float a = 0.f;
    #pragma unroll 8
    for (int c = 0; c < CFE; ++c) { float v = p[c * NPIX]; a = fmaf(v, v, a); }
    const float* q = sm + (size_t)b * CMA * NPIX + m;
    float am = 0.f;
    #pragma unroll
    for (int c = 0; c < CMA; ++c) { float v = q[c * NPIX]; am = fmaf(v, v, am); }
    psf[g] = a; psm[g] = am;
}

// 9-tap masked patch-norm -> reciprocal
__global__ __launch_bounds__(256)
void prnorm_kernel(const float* __restrict__ psf, const float* __restrict__ psm,
                   float* __restrict__ rnf, float* __restrict__ rnm) {
    int g = blockIdx.x * 256 + threadIdx.x;
    if (g >= 2 * NPIX) return;
    int b = g / NPIX, m = g - b * NPIX;
    int mh = m / WW, mw = m - mh * WW;
    float sF = 0.f, sM = 0.f;
    #pragma unroll
    for (int di = -1; di <= 1; ++di) {
        if ((unsigned)(mh + di) >= HH) continue;
        #pragma unroll
        for (int dj = -1; dj <= 1; ++dj) {
            if ((unsigned)(mw + dj) >= WW) continue;
            int mm = m + di * WW + dj;
            sF += psf[b * NPIX + mm];
            sM += psm[b * NPIX + mm];
        }
    }
    rnf[g] = 1.f / fmaxf(sqrtf(sF), 1e-12f);
    rnm[g] = 1.f / fmaxf(sqrtf(sM), 1e-12f);
}

// ---------------------------------------------------------------------------
// Pass 1: pixel dot-matrices. Sf[n][j] = sum_c cf[c,n]*sf[c,mlo+j] (K=64),
// Sm same over mask channels (K=3). No im2col, no masks -> trivial staging.
// ---------------------------------------------------------------------------
__global__ __launch_bounds__(256, 3)
void s0_kernel(const float* __restrict__ cf, const float* __restrict__ sf,
               const float* __restrict__ cm, const float* __restrict__ smk,
               float* __restrict__ Sf, float* __restrict__ Sm,
               int mlo, int Jw, int JST, int b0) {
    __shared__ __align__(16) float As[32][128];
    __shared__ __align__(16) float Bs[32][128];
    __shared__ __align__(16) float Amr[3][128];
    __shared__ __align__(16) float Bmr[3][128];

    const int bz = blockIdx.z, b = b0 + bz;
    const int n0 = blockIdx.y * 128;
    const int j0 = blockIdx.x * 128;
    const int tid = threadIdx.x;
    const int ty = tid >> 4, tx = tid & 15;
    const int wv = tid >> 6, ln = tid & 63;

    const float* __restrict__ cfb = cf + (size_t)b * CFE * NPIX;
    const float* __restrict__ sfb = sf + (size_t)b * CFE * NPIX;

    if (tid < 128) {
        int p = tid;
        int mm = mlo + j0 + p; if (mm > NPIX - 1) mm = NPIX - 1;
        const float* cmb = cm  + (size_t)b * CMA * NPIX;
        const float* smb = smk + (size_t)b * CMA * NPIX;
        #pragma unroll
        for (int c = 0; c < 3; ++c) {
            Amr[c][p] = cmb[c * NPIX + n0 + p];
            Bmr[c][p] = smb[c * NPIX + mm];
        }
    }

    float accF[8][8];
    #pragma unroll
    for (int i = 0; i < 8; ++i)
        #pragma unroll
        for (int j = 0; j < 8; ++j) accF[i][j] = 0.f;

    const int mB0 = (mlo + j0 + ln      > NPIX - 1) ? NPIX - 1 : mlo + j0 + ln;
    const int mB1 = (mlo + j0 + ln + 64 > NPIX - 1) ? NPIX - 1 : mlo + j0 + ln + 64;

    #pragma unroll 1
    for (int half = 0; half < 2; ++half) {
        __syncthreads();
        const int c0 = half * 32 + 8 * wv;
        {
            const float* g = cfb + (size_t)c0 * NPIX + (n0 + ln);
            float* dst = &As[8 * wv][0];
            #pragma unroll
            for (int r = 0; r < 8; ++r) { gload4(g, dst); g += NPIX; dst += 128; }
            g = cfb + (size_t)c0 * NPIX + (n0 + ln + 64);
            dst = &As[8 * wv][64];
            #pragma unroll
            for (int r = 0; r < 8; ++r) { gload4(g, dst); g += NPIX; dst += 128; }
            g = sfb + (size_t)c0 * NPIX + mB0;
            dst = &Bs[8 * wv][0];
            #pragma unroll
            for (int r = 0; r < 8; ++r) { gload4(g, dst); g += NPIX; dst += 128; }
            g = sfb + (size_t)c0 * NPIX + mB1;
            dst = &Bs[8 * wv][64];
            #pragma unroll
            for (int r = 0; r < 8; ++r) { gload4(g, dst); g += NPIX; dst += 128; }
        }
        __syncthreads();
        #pragma unroll 4
        for (int k = 0; k < 32; ++k) {
            float a[8], bb[8];
            *(float4*)&a[0]  = *(const float4*)&As[k][ty * 4];
            *(float4*)&a[4]  = *(const float4*)&As[k][64 + ty * 4];
            *(float4*)&bb[0] = *(const float4*)&Bs[k][tx * 4];
            *(float4*)&bb[4] = *(const float4*)&Bs[k][64 + tx * 4];
            #pragma unroll
            for (int i = 0; i < 8; ++i)
                #pragma unroll
                for (int j = 0; j < 8; ++j)
                    accF[i][j] = fmaf(a[i], bb[j], accF[i][j]);
        }
    }

    float accM[8][8];
    #pragma unroll
    for (int i = 0; i < 8; ++i)
        #pragma unroll
        for (int j = 0; j < 8; ++j) accM[i][j] = 0.f;
    #pragma unroll
    for (int k = 0; k < 3; ++k) {
        float a[8], bb[8];
        *(float4*)&a[0]  = *(const float4*)&Amr[k][ty * 4];
        *(float4*)&a[4]  = *(const float4*)&Amr[k][64 + ty * 4];
        *(float4*)&bb[0] = *(const float4*)&Bmr[k][tx * 4];
        *(float4*)&bb[4] = *(const float4*)&Bmr[k][64 + tx * 4];
        #pragma unroll
        for (int i = 0; i < 8; ++i)
            #pragma unroll
            for (int j = 0; j < 8; ++j)
                accM[i][j] = fmaf(a[i], bb[j], accM[i][j]);
    }

    // write tiles
    const size_t bq = (size_t)bz * NPIX * JST;
    #pragma unroll
    for (int i = 0; i < 8; ++i) {
        int ri = (i < 4) ? (ty * 4 + i) : (64 + ty * 4 + (i - 4));
        size_t row = bq + (size_t)(n0 + ri) * JST + j0;
        *(float4*)(Sf + row + tx * 4)      = make_float4(accF[i][0], accF[i][1], accF[i][2], accF[i][3]);
        *(float4*)(Sf + row + 64 + tx * 4) = make_float4(accF[i][4], accF[i][5], accF[i][6], accF[i][7]);
        *(float4*)(Sm + row + tx * 4)      = make_float4(accM[i][0], accM[i][1], accM[i][2], accM[i][3]);
        *(float4*)(Sm + row + 64 + tx * 4) = make_float4(accM[i][4], accM[i][5], accM[i][6], accM[i][7]);
    }
}

// ---------------------------------------------------------------------------
// Pass 2: 9-tap diagonal stencil + score + per-tile argmax.
// Thread t: rows R0 = (t>>4)*8 + i (contiguous 8), cols Cl=(t&15)*4 + j and 64+Cl+j.
// LDS square per diagonal cluster g: sq[r][c] = S[rbase+r][cb+c], cb = j0t+80g-5.
// ---------------------------------------------------------------------------
__global__ __launch_bounds__(256, 2)
void tap_kernel(const float* __restrict__ Sf, const float* __restrict__ Sm,
                const float* __restrict__ rnf, const float* __restrict__ rnm,
                float* __restrict__ pval, int* __restrict__ pidx,
                int m0, int mlo, int Jw, int JST, int b0) {
    __shared__ __align__(16) float sq[130][136];

    const int bz = blockIdx.z, b = b0 + bz;
    const int n0 = blockIdx.y * 128;
    const int m0t = m0 + blockIdx.x * 128;
    const int j0t = m0t - mlo;
    const int tid = threadIdx.x;
    const int R0 = (tid >> 4) * 8;
    const int Cl = (tid & 15) * 4;
    const float* __restrict__ SfB = Sf + (size_t)bz * NPIX * JST;
    const float* __restrict__ SmB = Sm + (size_t)bz * NPIX * JST;

    // validity masks: amask over 8 rows (bit i), bmL/bmH over 4 cols each (bit j)
    int nh[8], nw[8], qh[8], qw[8];
    #pragma unroll
    for (int i = 0; i < 8; ++i) { int n = n0 + R0 + i; nh[i] = n / 80; nw[i] = n - nh[i] * 80; }
    #pragma unroll
    for (int j = 0; j < 8; ++j) {
        int m = m0t + ((j < 4) ? (Cl + j) : (64 + Cl + j - 4));
        qh[j] = m / 80; qw[j] = m - qh[j] * 80;
    }
    int amask[3][3], bmL[3][3], bmH[3][3];
    #pragma unroll
    for (int g3 = 0; g3 < 3; ++g3)
        #pragma unroll
        for (int d1 = 0; d1 < 3; ++d1) {
            int am = 0, bl = 0, bh = 0;
            #pragma unroll
            for (int i = 0; i < 8; ++i)
                am |= (((unsigned)(nh[i] + g3 - 1) < HH) && ((unsigned)(nw[i] + d1 - 1) < WW)) << i;
            #pragma unroll
            for (int j = 0; j < 4; ++j) {
                bl |= (((unsigned)(qh[j] + g3 - 1) < HH) && ((unsigned)(qw[j] + d1 - 1) < WW)) << j;
                bh |= (((unsigned)(qh[4 + j] + g3 - 1) < HH) && ((unsigned)(qw[4 + j] + d1 - 1) < WW)) << j;
            }
            amask[g3][d1] = am; bmL[g3][d1] = bl; bmH[g3][d1] = bh;
        }

    float pdF[8][8], pdM[8][8];
    #pragma unroll
    for (int i = 0; i < 8; ++i)
        #pragma unroll
        for (int j = 0; j < 8; ++j) { pdF[i][j] = 0.f; pdM[i][j] = 0.f; }

    auto stage = [&](const float* __restrict__ Sp, int g3) {
        const int g = g3 - 1;
        const int rbase = n0 + 80 * g - 1;
        const int cb = j0t + 80 * g - 5;
        for (int e = tid; e < 130 * 34; e += 256) {
            int r = e / 34, c4 = e - r * 34;
            int rr = rbase + r; rr = rr < 0 ? 0 : (rr > NPIX - 1 ? NPIX - 1 : rr);
            int jj = cb + c4 * 4;
            const float* rp = Sp + (size_t)rr * JST;
            float4 v;
            if (jj >= 0 && jj + 4 <= Jw) {
                f4u t = *(const f4u*)(rp + jj);
                v = make_float4(t.x, t.y, t.z, t.w);
            } else {
                int a0 = jj;     a0 = a0 < 0 ? 0 : (a0 > Jw - 1 ? Jw - 1 : a0);
                int a1 = jj + 1; a1 = a1 < 0 ? 0 : (a1 > Jw - 1 ? Jw - 1 : a1);
                int a2 = jj + 2; a2 = a2 < 0 ? 0 : (a2 > Jw - 1 ? Jw - 1 : a2);
                int a3 = jj + 3; a3 = a3 < 0 ? 0 : (a3 > Jw - 1 ? Jw - 1 : a3);
                v = make_float4(rp[a0], rp[a1], rp[a2], rp[a3]);
            }
            *(float4*)&sq[r][c4 * 4] = v;
        }
    };

    auto accum = [&](float (&pd)[8][8], int g3) {
        #pragma unroll
        for (int r = 0; r < 10; ++r) {
            const float* row = &sq[R0 + r][0];
            float al[8], bl8[8];
            *(float4*)&al[0]  = *(const float4*)(row + Cl + 4);
            *(float4*)&al[4]  = *(const float4*)(row + Cl + 8);
            *(float4*)&bl8[0] = *(const float4*)(row + 64 + Cl + 4);
            *(float4*)&bl8[4] = *(const float4*)(row + 64 + Cl + 8);
            #pragma unroll
            for (int d1 = 0; d1 < 3; ++d1) {
                const int i = r - d1;
                if (i >= 0 && i < 8) {
                    if ((amask[g3][d1] >> i) & 1) {
                        const int bl = bmL[g3][d1], bh = bmH[g3][d1];
                        #pragma unroll
                        for (int j = 0; j < 4; ++j) {
                            float v = al[j + d1];  v = ((bl >> j) & 1) ? v : 0.f;  pd[i][j]     += v;
                            float w = bl8[j + d1]; w = ((bh >> j) & 1) ? w : 0.f;  pd[i][4 + j] += w;
                        }
                    }
                }
            }
        }
    };

    #pragma unroll
    for (int g3 = 0; g3 < 3; ++g3) {
        __syncthreads(); stage(SfB, g3); __syncthreads(); accum(pdF, g3);
        __syncthreads(); stage(SmB, g3); __syncthreads(); accum(pdM, g3);
    }

    // score + in-thread argmax (cols ascending per thread; strict > keeps first)
    float rvF[8], rvM[8];
    #pragma unroll
    for (int j = 0; j < 8; ++j) {
        int m = m0t + ((j < 4) ? (Cl + j) : (64 + Cl + j - 4));
        rvF[j] = rnf[b * NPIX + m]; rvM[j] = rnm[b * NPIX + m];
    }
    float bv[8]; int bi[8];
    #pragma unroll
    for (int i = 0; i < 8; ++i) { bv[i] = NEG_INF; bi[i] = 0x7fffffff; }
    #pragma unroll
    for (int j = 0; j < 8; ++j) {
        int m = m0t + ((j < 4) ? (Cl + j) : (64 + Cl + j - 4));
        #pragma unroll
        for (int i = 0; i < 8; ++i) {
            float s = (pdF[i][j] * rvF[j]) * (pdM[i][j] * rvM[j]);
            if (s > bv[i]) { bv[i] = s; bi[i] = m; }
        }
    }

    __syncthreads();
    float* rv2 = &sq[0][0];
    int*   ri2 = ((int*)&sq[0][0]) + 2048;
    #pragma unroll
    for (int i = 0; i < 8; ++i) {
        int r = R0 + i;
        rv2[r * 16 + (tid & 15)] = bv[i];
        ri2[r * 16 + (tid & 15)] = bi[i];
    }
    __syncthreads();
    if (tid < 128) {
        float best = rv2[tid * 16]; int besti = ri2[tid * 16];
        #pragma unroll 4
        for (int t = 1; t < 16; ++t) {
            float v = rv2[tid * 16 + t]; int ii = ri2[tid * 16 + t];
            if (v > best || (v == best && ii < besti)) { best = v; besti = ii; }
        }
        int n = n0 + tid;
        int mtg = m0t >> 7;
        pval[((size_t)b * NT + mtg) * NPIX + n] = best;
        pidx[((size_t)b * NT + mtg) * NPIX + n] = besti;
    }
}

// ---------------------------------------------------------------------------
// Final reduce over 50 m-tile partials + gather of the winning patch.
// ---------------------------------------------------------------------------
__global__ __launch_bounds__(64)
void gather_kernel(const float* __restrict__ sf,
                   const float* __restrict__ pval, const int* __restrict__ pidx,
                   float* __restrict__ out) {
    int n = blockIdx.x, b = blockIdx.y;
    int lane = threadIdx.x;

    float v = NEG_INF; int idx = 0x7fffffff;
    if (lane < NT) {
        v   = pval[((size_t)b * NT + lane) * NPIX + n];
        idx = pidx[((size_t)b * NT + lane) * NPIX + n];
    }
    #pragma unroll
    for (int off = 32; off >= 1; off >>= 1) {
        float ov = __shfl_xor(v, off);
        int   oi = __shfl_xor(idx, off);
        if (ov > v || (ov == v && oi < idx)) { v = ov; idx = oi; }
    }

    int m = idx; int mh = m / WW, mw = m - mh * WW;
    const float* sfb = sf + (size_t)b * CFE * NPIX;
    float* ob = out + ((size_t)b * NPIX + n) * (size_t)KF;
    #pragma unroll
    for (int e = lane; e < KF; e += 64) {
        int c = e / 9, pos = e - c * 9;
        int di = pos / 3 - 1, dj = pos - (pos / 3) * 3 - 1;
        int h = mh + di, w = mw + dj;
        ob[e] = ((unsigned)h < HH && (unsigned)w < WW) ? sfb[c * NPIX + h * WW + w] : 0.f;
    }
}

// ---------------------------------------------------------------------------
extern "C" void kernel_launch(void* const* d_in, const int* in_sizes, int n_in,
                              void* d_out, int out_size, void* d_ws, size_t ws_size,
                              hipStream_t stream) {
    const float* cf = (const float*)d_in[0];
    const float* sf = (const float*)d_in[1];
    const float* cm = (const float*)d_in[2];
    const float* sm = (const float*)d_in[3];
    float* out = (float*)d_out;

    float* rnf  = (float*)d_ws;
    float* rnm  = rnf + 2 * NPIX;
    float* psf  = rnm + 2 * NPIX;
    float* psm  = psf + 2 * NPIX;
    float* pval = psm + 2 * NPIX;
    int*   pidx = (int*)(pval + (size_t)2 * NT * NPIX);
    float* Sbase = (float*)(pidx + (size_t)2 * NT * NPIX);
    const size_t headf = (size_t)4 * 2 * NPIX + (size_t)2 * 2 * NT * NPIX;

    // strip ladder: pick largest config that fits ws
    static const int cfgNB[5] = {2, 2, 2, 1, 1};
    static const int cfgMc[5] = {1280, 640, 256, 256, 128};
    int NB = 1, Mc = 128, T = 3;
    for (int k = 0; k < 5; ++k) {
        int t = (cfgMc[k] + 165 + 127) / 128;   // Jw_max = Mc + 84 + 81
        size_t need = (headf + (size_t)cfgNB[k] * NPIX * (size_t)(t * 128) * 2) * 4;
        if (need <= ws_size || k == 4) { NB = cfgNB[k]; Mc = cfgMc[k]; T = t; if (need <= ws_size) break; }
    }
    const int JST = T * 128;
    float* Sf = Sbase;
    float* Sm = Sf + (size_t)NB * NPIX * JST;

    pixsq_kernel <<<(2 * NPIX + 255) / 256, 256, 0, stream>>>(sf, sm, psf, psm);
    prnorm_kernel<<<(2 * NPIX + 255) / 256, 256, 0, stream>>>(psf, psm, rnf, rnm);

    const int nstrip = NPIX / Mc;
    for (int s = 0; s < nstrip; ++s) {
        int m0  = s * Mc;
        int mlo = m0 - 84; if (mlo < 0) mlo = 0;
        int mhi = m0 + Mc + 81; if (mhi > NPIX) mhi = NPIX;
        int Jw = mhi - mlo;
        for (int bb = 0; bb < 2; bb += NB) {
            s0_kernel <<<dim3(T, 50, NB), 256, 0, stream>>>(cf, sf, cm, sm, Sf, Sm, mlo, Jw, JST, bb);
            tap_kernel<<<dim3(Mc / 128, 50, NB), 256, 0, stream>>>(Sf, Sm, rnf, rnm, pval, pidx,
                                                                   m0, mlo, Jw, JST, bb);
        }
    }
    gather_kernel<<<dim3(NPIX, 2), 64, 0, stream>>>(sf, pval, pidx, out);
}

// Round 4
// 930.786 us; speedup vs baseline: 1.8378x; 1.0047x over previous
//
#include <hip/hip_runtime.h>

#define HH 80
#define WW 80
#define NPIX 6400
#define CFE 64
#define CMA 3
#define KF 576
#define NT 50              // global 128-col tiles
#define NEG_INF (-__builtin_inff())

// 16B load with only 4B alignment guarantee (backend emits dwordx4; dword align ok)
struct f4u { float x, y, z, w; };

__device__ __forceinline__ void gload4(const float* g, float* l) {
    __builtin_amdgcn_global_load_lds((const __attribute__((address_space(1))) void*)g,
                                     (__attribute__((address_space(3))) void*)l, 4, 0, 0);
}

// ---------------------------------------------------------------------------
// per-pixel channel-sum-of-squares (style side only)
// ---------------------------------------------------------------------------
__global__ __launch_bounds__(256)
void pixsq_kernel(const float* __restrict__ sf, const float* __restrict__ sm,
                  float* __restrict__ psf, float* __restrict__ psm) {
    int g = blockIdx.x * 256 + threadIdx.x;
    if (g >= 2 * NPIX) return;
    int b = g / NPIX, m = g - b * NPIX;
    const float* p = sf + (size_t)b * CFE * NPIX + m;
    float a = 0.f;
    #pragma unroll 8
    for (int c = 0; c < CFE; ++c) { float v = p[c * NPIX]; a = fmaf(v, v, a); }
    const float* q = sm + (size_t)b * CMA * NPIX + m;
    float am = 0.f;
    #pragma unroll
    for (int c = 0; c < CMA; ++c) { float v = q[c * NPIX]; am = fmaf(v, v, am); }
    psf[g] = a; psm[g] = am;
}

// 9-tap masked patch-norm -> reciprocal
__global__ __launch_bounds__(256)
void prnorm_kernel(const float* __restrict__ psf, const float* __restrict__ psm,
                   float* __restrict__ rnf, float* __restrict__ rnm) {
    int g = blockIdx.x * 256 + threadIdx.x;
    if (g >= 2 * NPIX) return;
    int b = g / NPIX, m = g - b * NPIX;
    int mh = m / WW, mw = m - mh * WW;
    float sF = 0.f, sM = 0.f;
    #pragma unroll
    for (int di = -1; di <= 1; ++di) {
        if ((unsigned)(mh + di) >= HH) continue;
        #pragma unroll
        for (int dj = -1; dj <= 1; ++dj) {
            if ((unsigned)(mw + dj) >= WW) continue;
            int mm = m + di * WW + dj;
            sF += psf[b * NPIX + mm];
            sM += psm[b * NPIX + mm];
        }
    }
    rnf[g] = 1.f / fmaxf(sqrtf(sF), 1e-12f);
    rnm[g] = 1.f / fmaxf(sqrtf(sM), 1e-12f);
}

// ---------------------------------------------------------------------------
// Pass 1: pixel dot-matrices. Sf[n][j] = sum_c cf[c,n]*sf[c,mlo+j] (K=64),
// Sm same over mask channels (K=3). No im2col, no masks -> trivial staging.
// ---------------------------------------------------------------------------
__global__ __launch_bounds__(256, 3)
void s0_kernel(const float* __restrict__ cf, const float* __restrict__ sf,
               const float* __restrict__ cm, const float* __restrict__ smk,
               float* __restrict__ Sf, float* __restrict__ Sm,
               int mlo, int Jw, int JST, int b0) {
    __shared__ __align__(16) float As[32][128];
    __shared__ __align__(16) float Bs[32][128];
    __shared__ __align__(16) float Amr[3][128];
    __shared__ __align__(16) float Bmr[3][128];

    const int b = b0;
    const int n0 = blockIdx.y * 128;
    const int j0 = blockIdx.x * 128;
    const int tid = threadIdx.x;
    const int ty = tid >> 4, tx = tid & 15;
    const int wv = tid >> 6, ln = tid & 63;

    const float* __restrict__ cfb = cf + (size_t)b * CFE * NPIX;
    const float* __restrict__ sfb = sf + (size_t)b * CFE * NPIX;

    if (tid < 128) {
        int p = tid;
        int mm = mlo + j0 + p; if (mm > NPIX - 1) mm = NPIX - 1;
        const float* cmb = cm  + (size_t)b * CMA * NPIX;
        const float* smb = smk + (size_t)b * CMA * NPIX;
        #pragma unroll
        for (int c = 0; c < 3; ++c) {
            Amr[c][p] = cmb[c * NPIX + n0 + p];
            Bmr[c][p] = smb[c * NPIX + mm];
        }
    }

    float accF[8][8];
    #pragma unroll
    for (int i = 0; i < 8; ++i)
        #pragma unroll
        for (int j = 0; j < 8; ++j) accF[i][j] = 0.f;

    const int mB0 = (mlo + j0 + ln      > NPIX - 1) ? NPIX - 1 : mlo + j0 + ln;
    const int mB1 = (mlo + j0 + ln + 64 > NPIX - 1) ? NPIX - 1 : mlo + j0 + ln + 64;

    #pragma unroll 1
    for (int half = 0; half < 2; ++half) {
        __syncthreads();
        const int c0 = half * 32 + 8 * wv;
        {
            const float* g = cfb + (size_t)c0 * NPIX + (n0 + ln);
            float* dst = &As[8 * wv][0];
            #pragma unroll
            for (int r = 0; r < 8; ++r) { gload4(g, dst); g += NPIX; dst += 128; }
            g = cfb + (size_t)c0 * NPIX + (n0 + ln + 64);
            dst = &As[8 * wv][64];
            #pragma unroll
            for (int r = 0; r < 8; ++r) { gload4(g, dst); g += NPIX; dst += 128; }
            g = sfb + (size_t)c0 * NPIX + mB0;
            dst = &Bs[8 * wv][0];
            #pragma unroll
            for (int r = 0; r < 8; ++r) { gload4(g, dst); g += NPIX; dst += 128; }
            g = sfb + (size_t)c0 * NPIX + mB1;
            dst = &Bs[8 * wv][64];
            #pragma unroll
            for (int r = 0; r < 8; ++r) { gload4(g, dst); g += NPIX; dst += 128; }
        }
        __syncthreads();
        #pragma unroll 4
        for (int k = 0; k < 32; ++k) {
            float a[8], bb[8];
            *(float4*)&a[0]  = *(const float4*)&As[k][ty * 4];
            *(float4*)&a[4]  = *(const float4*)&As[k][64 + ty * 4];
            *(float4*)&bb[0] = *(const float4*)&Bs[k][tx * 4];
            *(float4*)&bb[4] = *(const float4*)&Bs[k][64 + tx * 4];
            #pragma unroll
            for (int i = 0; i < 8; ++i)
                #pragma unroll
                for (int j = 0; j < 8; ++j)
                    accF[i][j] = fmaf(a[i], bb[j], accF[i][j]);
        }
    }

    float accM[8][8];
    #pragma unroll
    for (int i = 0; i < 8; ++i)
        #pragma unroll
        for (int j = 0; j < 8; ++j) accM[i][j] = 0.f;
    #pragma unroll
    for (int k = 0; k < 3; ++k) {
        float a[8], bb[8];
        *(float4*)&a[0]  = *(const float4*)&Amr[k][ty * 4];
        *(float4*)&a[4]  = *(const float4*)&Amr[k][64 + ty * 4];
        *(float4*)&bb[0] = *(const float4*)&Bmr[k][tx * 4];
        *(float4*)&bb[4] = *(const float4*)&Bmr[k][64 + tx * 4];
        #pragma unroll
        for (int i = 0; i < 8; ++i)
            #pragma unroll
            for (int j = 0; j < 8; ++j)
                accM[i][j] = fmaf(a[i], bb[j], accM[i][j]);
    }

    // write tiles (single batch per launch -> no bz offset)
    #pragma unroll
    for (int i = 0; i < 8; ++i) {
        int ri = (i < 4) ? (ty * 4 + i) : (64 + ty * 4 + (i - 4));
        size_t row = (size_t)(n0 + ri) * JST + j0;
        *(float4*)(Sf + row + tx * 4)      = make_float4(accF[i][0], accF[i][1], accF[i][2], accF[i][3]);
        *(float4*)(Sf + row + 64 + tx * 4) = make_float4(accF[i][4], accF[i][5], accF[i][6], accF[i][7]);
        *(float4*)(Sm + row + tx * 4)      = make_float4(accM[i][0], accM[i][1], accM[i][2], accM[i][3]);
        *(float4*)(Sm + row + 64 + tx * 4) = make_float4(accM[i][4], accM[i][5], accM[i][6], accM[i][7]);
    }
}

// ---------------------------------------------------------------------------
// Pass 2: 9-tap diagonal stencil + score + per-tile argmax.
// ---------------------------------------------------------------------------
__global__ __launch_bounds__(256, 2)
void tap_kernel(const float* __restrict__ Sf, const float* __restrict__ Sm,
                const float* __restrict__ rnf, const float* __restrict__ rnm,
                float* __restrict__ pval, int* __restrict__ pidx,
                int m0, int mlo, int Jw, int JST, int b0) {
    __shared__ __align__(16) float sq[130][136];

    const int b = b0;
    const int n0 = blockIdx.y * 128;
    const int m0t = m0 + blockIdx.x * 128;
    const int j0t = m0t - mlo;
    const int tid = threadIdx.x;
    const int R0 = (tid >> 4) * 8;
    const int Cl = (tid & 15) * 4;
    const float* __restrict__ SfB = Sf;
    const float* __restrict__ SmB = Sm;

    // validity masks: amask over 8 rows (bit i), bmL/bmH over 4 cols each (bit j)
    int nh[8], nw[8], qh[8], qw[8];
    #pragma unroll
    for (int i = 0; i < 8; ++i) { int n = n0 + R0 + i; nh[i] = n / 80; nw[i] = n - nh[i] * 80; }
    #pragma unroll
    for (int j = 0; j < 8; ++j) {
        int m = m0t + ((j < 4) ? (Cl + j) : (64 + Cl + j - 4));
        qh[j] = m / 80; qw[j] = m - qh[j] * 80;
    }
    int amask[3][3], bmL[3][3], bmH[3][3];
    #pragma unroll
    for (int g3 = 0; g3 < 3; ++g3)
        #pragma unroll
        for (int d1 = 0; d1 < 3; ++d1) {
            int am = 0, bl = 0, bh = 0;
            #pragma unroll
            for (int i = 0; i < 8; ++i)
                am |= (((unsigned)(nh[i] + g3 - 1) < HH) && ((unsigned)(nw[i] + d1 - 1) < WW)) << i;
            #pragma unroll
            for (int j = 0; j < 4; ++j) {
                bl |= (((unsigned)(qh[j] + g3 - 1) < HH) && ((unsigned)(qw[j] + d1 - 1) < WW)) << j;
                bh |= (((unsigned)(qh[4 + j] + g3 - 1) < HH) && ((unsigned)(qw[4 + j] + d1 - 1) < WW)) << j;
            }
            amask[g3][d1] = am; bmL[g3][d1] = bl; bmH[g3][d1] = bh;
        }

    float pdF[8][8], pdM[8][8];
    #pragma unroll
    for (int i = 0; i < 8; ++i)
        #pragma unroll
        for (int j = 0; j < 8; ++j) { pdF[i][j] = 0.f; pdM[i][j] = 0.f; }

    auto stage = [&](const float* __restrict__ Sp, int g3) {
        const int g = g3 - 1;
        const int rbase = n0 + 80 * g - 1;
        const int cb = j0t + 80 * g - 5;
        const bool rin = (rbase >= 0) && (rbase + 130 <= NPIX);
        const bool cin = (cb >= 0) && (cb + 136 <= Jw);
        if (rin && cin) {
            // interior fast path: pure rectangular copy, no clamps
            const float* base = Sp + (size_t)rbase * JST + cb;
            for (int e = tid; e < 130 * 34; e += 256) {
                int r = e / 34, c4 = e - r * 34;
                f4u t = *(const f4u*)(base + (size_t)r * JST + c4 * 4);
                *(float4*)&sq[r][c4 * 4] = make_float4(t.x, t.y, t.z, t.w);
            }
        } else {
            for (int e = tid; e < 130 * 34; e += 256) {
                int r = e / 34, c4 = e - r * 34;
                int rr = rbase + r; rr = rr < 0 ? 0 : (rr > NPIX - 1 ? NPIX - 1 : rr);
                int jj = cb + c4 * 4;
                const float* rp = Sp + (size_t)rr * JST;
                float4 v;
                if (jj >= 0 && jj + 4 <= Jw) {
                    f4u t = *(const f4u*)(rp + jj);
                    v = make_float4(t.x, t.y, t.z, t.w);
                } else {
                    int a0 = jj;     a0 = a0 < 0 ? 0 : (a0 > Jw - 1 ? Jw - 1 : a0);
                    int a1 = jj + 1; a1 = a1 < 0 ? 0 : (a1 > Jw - 1 ? Jw - 1 : a1);
                    int a2 = jj + 2; a2 = a2 < 0 ? 0 : (a2 > Jw - 1 ? Jw - 1 : a2);
                    int a3 = jj + 3; a3 = a3 < 0 ? 0 : (a3 > Jw - 1 ? Jw - 1 : a3);
                    v = make_float4(rp[a0], rp[a1], rp[a2], rp[a3]);
                }
                *(float4*)&sq[r][c4 * 4] = v;
            }
        }
    };

    auto accum = [&](float (&pd)[8][8], int g3) {
        #pragma unroll
        for (int r = 0; r < 10; ++r) {
            const float* row = &sq[R0 + r][0];
            float al[8], bl8[8];
            *(float4*)&al[0]  = *(const float4*)(row + Cl + 4);
            *(float4*)&al[4]  = *(const float4*)(row + Cl + 8);
            *(float4*)&bl8[0] = *(const float4*)(row + 64 + Cl + 4);
            *(float4*)&bl8[4] = *(const float4*)(row + 64 + Cl + 8);
            #pragma unroll
            for (int d1 = 0; d1 < 3; ++d1) {
                const int i = r - d1;
                if (i >= 0 && i < 8) {
                    if ((amask[g3][d1] >> i) & 1) {
                        const int bl = bmL[g3][d1], bh = bmH[g3][d1];
                        #pragma unroll
                        for (int j = 0; j < 4; ++j) {
                            float v = al[j + d1];  v = ((bl >> j) & 1) ? v : 0.f;  pd[i][j]     += v;
                            float w = bl8[j + d1]; w = ((bh >> j) & 1) ? w : 0.f;  pd[i][4 + j] += w;
                        }
                    }
                }
            }
        }
    };

    #pragma unroll
    for (int g3 = 0; g3 < 3; ++g3) {
        __syncthreads(); stage(SfB, g3); __syncthreads(); accum(pdF, g3);
        __syncthreads(); stage(SmB, g3); __syncthreads(); accum(pdM, g3);
    }

    // score + in-thread argmax (cols ascending per thread; strict > keeps first)
    float rvF[8], rvM[8];
    #pragma unroll
    for (int j = 0; j < 8; ++j) {
        int m = m0t + ((j < 4) ? (Cl + j) : (64 + Cl + j - 4));
        rvF[j] = rnf[b * NPIX + m]; rvM[j] = rnm[b * NPIX + m];
    }
    float bv[8]; int bi[8];
    #pragma unroll
    for (int i = 0; i < 8; ++i) { bv[i] = NEG_INF; bi[i] = 0x7fffffff; }
    #pragma unroll
    for (int j = 0; j < 8; ++j) {
        int m = m0t + ((j < 4) ? (Cl + j) : (64 + Cl + j - 4));
        #pragma unroll
        for (int i = 0; i < 8; ++i) {
            float s = (pdF[i][j] * rvF[j]) * (pdM[i][j] * rvM[j]);
            if (s > bv[i]) { bv[i] = s; bi[i] = m; }
        }
    }

    __syncthreads();
    float* rv2 = &sq[0][0];
    int*   ri2 = ((int*)&sq[0][0]) + 2048;
    #pragma unroll
    for (int i = 0; i < 8; ++i) {
        int r = R0 + i;
        rv2[r * 16 + (tid & 15)] = bv[i];
        ri2[r * 16 + (tid & 15)] = bi[i];
    }
    __syncthreads();
    if (tid < 128) {
        float best = rv2[tid * 16]; int besti = ri2[tid * 16];
        #pragma unroll 4
        for (int t = 1; t < 16; ++t) {
            float v = rv2[tid * 16 + t]; int ii = ri2[tid * 16 + t];
            if (v > best || (v == best && ii < besti)) { best = v; besti = ii; }
        }
        int n = n0 + tid;
        int mtg = m0t >> 7;
        pval[((size_t)b * NT + mtg) * NPIX + n] = best;
        pidx[((size_t)b * NT + mtg) * NPIX + n] = besti;
    }
}

// ---------------------------------------------------------------------------
// Final reduce over 50 m-tile partials + gather of the winning patch.
// ---------------------------------------------------------------------------
__global__ __launch_bounds__(64)
void gather_kernel(const float* __restrict__ sf,
                   const float* __restrict__ pval, const int* __restrict__ pidx,
                   float* __restrict__ out) {
    int n = blockIdx.x, b = blockIdx.y;
    int lane = threadIdx.x;

    float v = NEG_INF; int idx = 0x7fffffff;
    if (lane < NT) {
        v   = pval[((size_t)b * NT + lane) * NPIX + n];
        idx = pidx[((size_t)b * NT + lane) * NPIX + n];
    }
    #pragma unroll
    for (int off = 32; off >= 1; off >>= 1) {
        float ov = __shfl_xor(v, off);
        int   oi = __shfl_xor(idx, off);
        if (ov > v || (ov == v && oi < idx)) { v = ov; idx = oi; }
    }

    int m = idx; int mh = m / WW, mw = m - mh * WW;
    const float* sfb = sf + (size_t)b * CFE * NPIX;
    float* ob = out + ((size_t)b * NPIX + n) * (size_t)KF;
    #pragma unroll
    for (int e = lane; e < KF; e += 64) {
        int c = e / 9, pos = e - c * 9;
        int di = pos / 3 - 1, dj = pos - (pos / 3) * 3 - 1;
        int h = mh + di, w = mw + dj;
        ob[e] = ((unsigned)h < HH && (unsigned)w < WW) ? sfb[c * NPIX + h * WW + w] : 0.f;
    }
}

// ---------------------------------------------------------------------------
extern "C" void kernel_launch(void* const* d_in, const int* in_sizes, int n_in,
                              void* d_out, int out_size, void* d_ws, size_t ws_size,
                              hipStream_t stream) {
    const float* cf = (const float*)d_in[0];
    const float* sf = (const float*)d_in[1];
    const float* cm = (const float*)d_in[2];
    const float* sm = (const float*)d_in[3];
    float* out = (float*)d_out;

    float* rnf  = (float*)d_ws;
    float* rnm  = rnf + 2 * NPIX;
    float* psf  = rnm + 2 * NPIX;
    float* psm  = psf + 2 * NPIX;
    float* pval = psm + 2 * NPIX;
    int*   pidx = (int*)(pval + (size_t)2 * NT * NPIX);
    float* Sbase = (float*)(pidx + (size_t)2 * NT * NPIX);
    const size_t headf = (size_t)4 * 2 * NPIX + (size_t)2 * 2 * NT * NPIX;

    // strip ladder (all single-batch): keep strip (Sf+Sm) small enough to be
    // L3-resident between the s0 write and the tap read.
    static const int cfgMc[4] = {1280, 640, 256, 128};
    static const int cfgT[4]  = {12, 7, 4, 3};
    int Mc = 128, T = 3;
    for (int k = 0; k < 4; ++k) {
        size_t need = (headf + (size_t)NPIX * (size_t)(cfgT[k] * 128) * 2) * 4;
        if (need <= ws_size || k == 3) { Mc = cfgMc[k]; T = cfgT[k]; break; }
    }
    const int JST = T * 128;
    float* Sf = Sbase;
    float* Sm = Sf + (size_t)NPIX * JST;

    pixsq_kernel <<<(2 * NPIX + 255) / 256, 256, 0, stream>>>(sf, sm, psf, psm);
    prnorm_kernel<<<(2 * NPIX + 255) / 256, 256, 0, stream>>>(psf, psm, rnf, rnm);

    const int nstrip = NPIX / Mc;
    for (int s = 0; s < nstrip; ++s) {
        int m0  = s * Mc;
        int mlo = m0 - 84; if (mlo < 0) mlo = 0;
        int mhi = m0 + Mc + 81; if (mhi > NPIX) mhi = NPIX;
        int Jw = mhi - mlo;
        for (int bb = 0; bb < 2; ++bb) {
            s0_kernel <<<dim3(T, 50, 1), 256, 0, stream>>>(cf, sf, cm, sm, Sf, Sm, mlo, Jw, JST, bb);
            tap_kernel<<<dim3(Mc / 128, 50, 1), 256, 0, stream>>>(Sf, Sm, rnf, rnm, pval, pidx,
                                                                  m0, mlo, Jw, JST, bb);
        }
    }
    gather_kernel<<<dim3(NPIX, 2), 64, 0, stream>>>(sf, pval, pidx, out);
}